// Round 9
// baseline (263.081 us; speedup 1.0000x reference)
//
#include <hip/hip_runtime.h>

namespace {

constexpr int BD = 2;
constexpr int DD = 160, HH = 192, WW = 224;
constexpr float INV_WIN = 1.0f / 729.0f;
constexpr float EPSV = 1e-5f;

constexpr int TH = 16, TW = 16;          // output tile (H x W)
constexpr int DC = 16;                   // output planes per d-chunk
constexpr int NREAL = DC + 8;            // 24 planes; pipeline runs 26 steps
constexpr int NSTEP = NREAL + 2;
constexpr int NCH = DD / DC;             // 10
constexpr int GX = WW / TW;              // 14
constexpr int GY = HH / TH;              // 12
constexpr int GZ = BD * NCH;             // 20
constexpr int NBLK = GX * GY * GZ;       // 3360
constexpr double NTOT = (double)BD * DD * HH * WW;

// srow (per parity buffer): [field][w*28 + row], rows 0..23 (pad 28).
// SR_FS=452 (f-shift /4 = 113 == 1 mod 8). Audited: S2 b32 scatter-writes
// exactly 2/bank per wave; S3 b128 reads uniform 8/quad. Parity-buffer
// offsets are wave-uniform (no bank effect). SR_BUF padded to 2280 (16B mult).
constexpr int SR_FS = 452;
constexpr int SR_BUF = 2280;
// scol (per parity buffer): [field][w*20 + o]. SC_FS=324. S3 b128 writes
// uniform 8/quad; S4 b32 reads exactly 2/bank. SC_BUF = 1620.
constexpr int SC_FS = 324;
constexpr int SC_BUF = 1620;

} // namespace

__global__ __launch_bounds__(256)
void ncc_fused(const float* __restrict__ x, const float* __restrict__ y,
               float* __restrict__ bsum) {
  const int tid = threadIdx.x;
  const int w0 = blockIdx.x * TW;
  const int h0 = blockIdx.y * TH;
  const int zb = blockIdx.z;
  const int b  = zb / NCH;
  const int d0 = (zb - b * NCH) * DC;

  __shared__ __align__(16) float srowF[2][SR_BUF];   // 18240 B (parity dbuf)
  __shared__ __align__(16) float scolF[2][SC_BUF];   // 12960 B (parity dbuf)
  __shared__ float swsum[4];

  // ---- S2 role: tids 0..95 (wave0 + wave1 lower half) = 24 rows x 4 segs.
  // 12-wide register window -> 4 sliding 9-tap W-sums x 5 fields.
  const bool s2a = tid < 96;
  const int r2  = tid >> 2;            // input row 0..23
  const int seg = tid & 3;
  const int gh  = h0 - 4 + r2;
  const int gw0 = w0 - 4 + seg * 4;    // 16B aligned
  const bool hok = (unsigned)gh < (unsigned)HH;
  const bool fastw = (gw0 >= 0) && (gw0 + 11 < WW);
  const unsigned plane = (unsigned)HH * WW;

  auto prefetch = [&](int s, float4* vx, float4* vy) {
    const int din = d0 - 4 + s;
    const float4 z = make_float4(0.f, 0.f, 0.f, 0.f);
    vx[0] = vx[1] = vx[2] = z;
    vy[0] = vy[1] = vy[2] = z;
    if (s2a && hok && (s < NREAL) && (din >= 0) && (din < DD)) {
      const unsigned rb = ((unsigned)b * DD + (unsigned)din) * plane + (unsigned)gh * WW;
      if (fastw) {
        const float4* px = (const float4*)(x + rb + gw0);
        const float4* py = (const float4*)(y + rb + gw0);
        vx[0] = px[0]; vx[1] = px[1]; vx[2] = px[2];
        vy[0] = py[0]; vy[1] = py[1]; vy[2] = py[2];
      } else {
        float* fx = (float*)vx;
        float* fy = (float*)vy;
#pragma unroll
        for (int e = 0; e < 12; ++e) {
          const int gw = gw0 + e;
          if ((unsigned)gw < (unsigned)WW) {
            fx[e] = x[rb + gw];
            fy[e] = y[rb + gw];
          }
        }
      }
    }
  };

  // ---- S3 role: tids 128..207 (wave2 full + wave3 lanes 0..15) = 5 f x 16 w.
  // No wave executes both S2 and S3 streams (divergence-aligned).
  const bool s3a = (tid >= 128) && (tid < 208);
  const int t3  = tid - 128;
  const int f3  = t3 >> 4;
  const int wl3 = t3 & 15;

  const int ow = tid & 15;
  const int oh = tid >> 4;

  // D-ring: 9 slots x 5 fields; slot indices static after full unroll.
  float rg0[9], rg1[9], rg2[9], rg3[9], rg4[9];
#pragma unroll
  for (int k = 0; k < 9; ++k) { rg0[k]=0.f; rg1[k]=0.f; rg2[k]=0.f; rg3[k]=0.f; rg4[k]=0.f; }
  float a0=0.f, a1=0.f, a2=0.f, a3=0.f, a4=0.f;
  float lsum = 0.0f;

  float4 px4[3], py4[3];
  prefetch(0, px4, py4);

  // 3-deep pipeline, ONE barrier per step:
  //   S4(plane s-2) ; S2(plane s) || S3(plane s-1) ; barrier.
  // Hazards (all separated by >=1 barrier, parities alternate):
  //   S2(s)->srow[s&1], read by S3(s+1)            : barrier end-of-s.
  //   S3(s-1)->scol[(s-1)&1], read by S4 in s+1    : barrier end-of-s.
  //   S4(s-2) reads scol[s&1], rewritten by S3(s+1): barrier end-of-s.
  //   S3(s+1) reads srow[s&1], rewritten by S2(s+2): barrier end-of-s+1.
#pragma unroll
  for (int s = 0; s < NSTEP; ++s) {
    // prefetch plane s+1 for S2's next step (latency hidden by whole step)
    float4 nx4[3], ny4[3];
    prefetch(s + 1, nx4, ny4);

    // ---- S4 (plane s-2): ring update + emit (all 256 threads, cheap)
    if (s >= 2) {
      const int ps = s - 2;
      const int sl = ps % 9;
      const float* cp = &scolF[ps & 1][ow * 20 + oh];
      const float g0 = cp[0*SC_FS], g1 = cp[1*SC_FS], g2 = cp[2*SC_FS],
                  g3 = cp[3*SC_FS], g4 = cp[4*SC_FS];
      a0 += g0 - rg0[sl]; rg0[sl] = g0;
      a1 += g1 - rg1[sl]; rg1[sl] = g1;
      a2 += g2 - rg2[sl]; rg2[sl] = g2;
      a3 += g3 - rg3[sl]; rg3[sl] = g3;
      a4 += g4 - rg4[sl]; rg4[sl] = g4;
      if (ps >= 8) {
        const float cross = fmaf(-a0 * INV_WIN, a1, a4);
        const float iv = fmaxf(fmaf(-a0 * INV_WIN, a0, a2), EPSV);
        const float jv = fmaxf(fmaf(-a1 * INV_WIN, a1, a3), EPSV);
        lsum += (cross * cross) / (iv * jv);
      }
    }

    // ---- S2 (plane s): W-sums -> srow[s&1] (waves 0-1 only)
    if (s < NREAL && s2a) {
      float xv[12], yv[12];
#pragma unroll
      for (int k = 0; k < 3; ++k) {
        *(float4*)&xv[4 * k] = px4[k];
        *(float4*)&yv[4 * k] = py4[k];
      }
      float s0=0.f, s1=0.f, s2=0.f, s3=0.f, s4=0.f;
#pragma unroll
      for (int k = 0; k < 9; ++k) {
        s0 += xv[k]; s1 += yv[k];
        s2 = fmaf(xv[k], xv[k], s2);
        s3 = fmaf(yv[k], yv[k], s3);
        s4 = fmaf(xv[k], yv[k], s4);
      }
      float* wb = &srowF[s & 1][(seg * 4) * 28 + r2];
      wb[0 * SR_FS] = s0; wb[1 * SR_FS] = s1; wb[2 * SR_FS] = s2;
      wb[3 * SR_FS] = s3; wb[4 * SR_FS] = s4;
#pragma unroll
      for (int t = 1; t < 4; ++t) {
        const float xn = xv[8 + t], xo = xv[t - 1];
        const float yn = yv[8 + t], yo = yv[t - 1];
        s0 += xn - xo;
        s1 += yn - yo;
        s2 += fmaf(xn, xn, -(xo * xo));
        s3 += fmaf(yn, yn, -(yo * yo));
        s4 += fmaf(xn, yn, -(xo * yo));
        float* wt = wb + t * 28;
        wt[0 * SR_FS] = s0; wt[1 * SR_FS] = s1; wt[2 * SR_FS] = s2;
        wt[3 * SR_FS] = s3; wt[4 * SR_FS] = s4;
      }
    }

    // ---- S3 (plane s-1): H-sums srow[(s-1)&1] -> scol[(s-1)&1] (waves 2-3)
    if (s >= 1 && s <= NREAL && s3a) {
      const float* rp = &srowF[(s - 1) & 1][f3 * SR_FS + wl3 * 28];
      float rv[24];
#pragma unroll
      for (int t = 0; t < 6; ++t) *(float4*)&rv[4 * t] = *(const float4*)&rp[4 * t];
      float acc = rv[0];
#pragma unroll
      for (int t = 1; t < 9; ++t) acc += rv[t];
      float ov[16];
      ov[0] = acc;
#pragma unroll
      for (int o = 1; o < 16; ++o) { acc += rv[o + 8] - rv[o - 1]; ov[o] = acc; }
      float* cp = &scolF[(s - 1) & 1][f3 * SC_FS + wl3 * 20];
#pragma unroll
      for (int t = 0; t < 4; ++t)
        *(float4*)&cp[4 * t] = make_float4(ov[4*t], ov[4*t+1], ov[4*t+2], ov[4*t+3]);
    }

    __syncthreads();
#pragma unroll
    for (int k = 0; k < 3; ++k) { px4[k] = nx4[k]; py4[k] = ny4[k]; }
  }

  // ---- block reduction
#pragma unroll
  for (int off = 32; off > 0; off >>= 1) lsum += __shfl_down(lsum, off);
  if ((tid & 63) == 0) swsum[tid >> 6] = lsum;
  __syncthreads();
  if (tid == 0) {
    const int bid = ((int)blockIdx.z * GY + (int)blockIdx.y) * GX + (int)blockIdx.x;
    bsum[bid] = swsum[0] + swsum[1] + swsum[2] + swsum[3];
  }
}

__global__ __launch_bounds__(256)
void ncc_finalize(const float* __restrict__ bsum, float* __restrict__ out) {
  double s = 0.0;
  for (int i = threadIdx.x; i < NBLK; i += 256) s += (double)bsum[i];
#pragma unroll
  for (int off = 32; off > 0; off >>= 1) s += __shfl_down(s, off);
  __shared__ double sh[4];
  if ((threadIdx.x & 63) == 0) sh[threadIdx.x >> 6] = s;
  __syncthreads();
  if (threadIdx.x == 0)
    out[0] = (float)(-(sh[0] + sh[1] + sh[2] + sh[3]) / NTOT);
}

extern "C" void kernel_launch(void* const* d_in, const int* in_sizes, int n_in,
                              void* d_out, int out_size, void* d_ws, size_t ws_size,
                              hipStream_t stream) {
  const float* x = (const float*)d_in[0];
  const float* y = (const float*)d_in[1];
  float* bsum = (float*)d_ws;          // 3360 floats, fully rewritten every call
  float* out  = (float*)d_out;

  dim3 grid(GX, GY, GZ);
  ncc_fused<<<grid, dim3(256), 0, stream>>>(x, y, bsum);
  ncc_finalize<<<1, dim3(256), 0, stream>>>(bsum, out);
}

// Round 10
// 209.153 us; speedup vs baseline: 1.2578x; 1.2578x over previous
//
#include <hip/hip_runtime.h>

namespace {

constexpr int BD = 2;
constexpr int DD = 160, HH = 192, WW = 224;
constexpr float INV_WIN = 1.0f / 729.0f;
constexpr float EPSV = 1e-5f;

constexpr int TH = 16, TW = 16;          // output tile (H x W)
constexpr int DC = 32;                   // output planes per d-chunk
constexpr int NREAL = DC + 8;            // 40 planes = 20 pairs
constexpr int NPAIR = NREAL / 2;         // 20
constexpr int NCH = DD / DC;             // 5
constexpr int GX = WW / TW;              // 14
constexpr int GY = HH / TH;              // 12
constexpr int GZ = BD * NCH;             // 10
constexpr int NBLK = GX * GY * GZ;       // 1680
constexpr double NTOT = (double)BD * DD * HH * WW;

// srow: [buf][plane][field][w*28 + row], rows 0..23 contiguous (pad 28).
// SR_FS=452, SR_PL=2280 — bank-audited in r7/r8: S2 b32 scatter 2/bank,
// S3 b128 reads uniform per quad. Pair-buffer stride wave-uniform.
constexpr int SR_FS = 452;
constexpr int SR_PL = 2280;
// scol: [plane][field][w*20 + o]. S3 b128 writes uniform; S4 b32 2/bank.
constexpr int SC_FS = 324;
constexpr int SC_PL = 1620;

} // namespace

__global__ __launch_bounds__(256)
void ncc_fused(const float* __restrict__ x, const float* __restrict__ y,
               float* __restrict__ bsum) {
  const int tid = threadIdx.x;
  const int w0 = blockIdx.x * TW;
  const int h0 = blockIdx.y * TH;
  const int zb = blockIdx.z;
  const int b  = zb / NCH;
  const int d0 = (zb - b * NCH) * DC;

  __shared__ __align__(16) float srowF[2][2 * SR_PL];  // 36480 B (pair dbuf)
  __shared__ __align__(16) float scolF[2 * SC_PL];     // 12960 B
  __shared__ float swsum[4];

  // ---- S2 roles: tids 0..191 = 2 planes x 24 rows x 4 col-segments.
  const bool s2a = tid < 192;
  const int p2  = tid / 96;
  const int t96 = tid - 96 * p2;
  const int r2  = t96 >> 2;            // input row 0..23
  const int seg = tid & 3;
  const int gh  = h0 - 4 + r2;
  const int gw0 = w0 - 4 + seg * 4;    // 16B aligned
  const bool hok = (unsigned)gh < (unsigned)HH;
  const bool fastw = (gw0 >= 0) && (gw0 + 11 < WW);
  const unsigned plane = (unsigned)HH * WW;

  auto prefetch = [&](int s, float4 (&vx)[3], float4 (&vy)[3]) {
    const int din = d0 - 4 + s;
    const float4 z = make_float4(0.f, 0.f, 0.f, 0.f);
    vx[0] = vx[1] = vx[2] = z;
    vy[0] = vy[1] = vy[2] = z;
    if (s2a && hok && (s < NREAL) && (din >= 0) && (din < DD)) {
      const unsigned rb = ((unsigned)b * DD + (unsigned)din) * plane + (unsigned)gh * WW;
      if (fastw) {
        const float4* px = (const float4*)(x + rb + gw0);
        const float4* py = (const float4*)(y + rb + gw0);
        vx[0] = px[0]; vx[1] = px[1]; vx[2] = px[2];
        vy[0] = py[0]; vy[1] = py[1]; vy[2] = py[2];
      } else {
        float* fx = (float*)vx;
        float* fy = (float*)vy;
#pragma unroll
        for (int e = 0; e < 12; ++e) {
          const int gw = gw0 + e;
          if ((unsigned)gw < (unsigned)WW) {
            fx[e] = x[rb + gw];
            fy[e] = y[rb + gw];
          }
        }
      }
    }
  };

  // ---- S3 roles: tids 96..255 = 2 planes x 5 fields x 16 w.
  const int t3  = tid - 96;
  const int p3  = t3 / 80;
  const int r3  = t3 - 80 * p3;
  const int f3  = r3 >> 4;
  const int wl3 = r3 & 15;

  const int ow = tid & 15;
  const int oh = tid >> 4;

  // D-ring: 9 slots x 5 fields, rotate-by-2 per superstep (r4-proven).
  float rg0[9], rg1[9], rg2[9], rg3[9], rg4[9];
#pragma unroll
  for (int k = 0; k < 9; ++k) { rg0[k]=0.f; rg1[k]=0.f; rg2[k]=0.f; rg3[k]=0.f; rg4[k]=0.f; }
  float a0=0.f, a1=0.f, a2=0.f, a3=0.f, a4=0.f;
  float lsum = 0.0f;

  // Superstep body (skewed pipeline, r8-proven):
  //   S2(pair ss) -> srow[ss&1]  ||  S3(pair ss-1) -> scol ; barrier C ;
  //   S4(pair ss-1) ; barrier E.
  // PX/PY hold pair ss's preloaded windows; after consuming them we reissue
  // the SAME buffer for pair ss+2 (distance-2 prefetch: the vmcnt wait for
  // those loads happens 2 supersteps later, ~2600 cy >> HBM latency).
  auto body = [&](int ss, bool doS2, float4 (&PX)[3], float4 (&PY)[3]) {
    if (doS2 && s2a) {
      float xv[12], yv[12];
#pragma unroll
      for (int k = 0; k < 3; ++k) {
        *(float4*)&xv[4 * k] = PX[k];
        *(float4*)&yv[4 * k] = PY[k];
      }
      // buffer consumed -> immediately reissue for pair ss+2
      prefetch(2 * (ss + 2) + p2, PX, PY);

      float s0=0.f, s1=0.f, s2=0.f, s3=0.f, s4=0.f;
#pragma unroll
      for (int k = 0; k < 9; ++k) {
        s0 += xv[k]; s1 += yv[k];
        s2 = fmaf(xv[k], xv[k], s2);
        s3 = fmaf(yv[k], yv[k], s3);
        s4 = fmaf(xv[k], yv[k], s4);
      }
      float* wb = &srowF[ss & 1][p2 * SR_PL + (seg * 4) * 28 + r2];
      wb[0 * SR_FS] = s0; wb[1 * SR_FS] = s1; wb[2 * SR_FS] = s2;
      wb[3 * SR_FS] = s3; wb[4 * SR_FS] = s4;
#pragma unroll
      for (int t = 1; t < 4; ++t) {
        const float xn = xv[8 + t], xo = xv[t - 1];
        const float yn = yv[8 + t], yo = yv[t - 1];
        s0 += xn - xo;
        s1 += yn - yo;
        s2 += fmaf(xn, xn, -(xo * xo));
        s3 += fmaf(yn, yn, -(yo * yo));
        s4 += fmaf(xn, yn, -(xo * yo));
        float* wt = wb + t * 28;
        wt[0 * SR_FS] = s0; wt[1 * SR_FS] = s1; wt[2 * SR_FS] = s2;
        wt[3 * SR_FS] = s3; wt[4 * SR_FS] = s4;
      }
    }

    // ---- S3 (pair ss-1): srow[(ss-1)&1] -> scol (tids 96..255).
    if (ss >= 1 && tid >= 96) {
      const float* rp = &srowF[(ss - 1) & 1][p3 * SR_PL + f3 * SR_FS + wl3 * 28];
      float rv[24];
#pragma unroll
      for (int t = 0; t < 6; ++t) *(float4*)&rv[4 * t] = *(const float4*)&rp[4 * t];
      float acc = rv[0];
#pragma unroll
      for (int t = 1; t < 9; ++t) acc += rv[t];
      float ov[16];
      ov[0] = acc;
#pragma unroll
      for (int o = 1; o < 16; ++o) { acc += rv[o + 8] - rv[o - 1]; ov[o] = acc; }
      float* cp = &scolF[p3 * SC_PL + f3 * SC_FS + wl3 * 20];
#pragma unroll
      for (int t = 0; t < 4; ++t)
        *(float4*)&cp[4 * t] = make_float4(ov[4*t], ov[4*t+1], ov[4*t+2], ov[4*t+3]);
    }
    __syncthreads();   // C: scol visible; orders S2 writes vs next S3 reads

    // ---- S4 (pair ss-1): ring update + emit (all 256 threads)
    if (ss >= 1) {
      const int ps = ss - 1;
      const float* cA = &scolF[ow * 20 + oh];
      const float* cB = cA + SC_PL;
      const float gA0 = cA[0*SC_FS], gA1 = cA[1*SC_FS], gA2 = cA[2*SC_FS],
                  gA3 = cA[3*SC_FS], gA4 = cA[4*SC_FS];
      const float gB0 = cB[0*SC_FS], gB1 = cB[1*SC_FS], gB2 = cB[2*SC_FS],
                  gB3 = cB[3*SC_FS], gB4 = cB[4*SC_FS];

      a0 += gA0 - rg0[0]; a1 += gA1 - rg1[0]; a2 += gA2 - rg2[0];
      a3 += gA3 - rg3[0]; a4 += gA4 - rg4[0];
      if (ps >= 4) {
        const float cross = fmaf(-a0 * INV_WIN, a1, a4);
        const float iv = fmaxf(fmaf(-a0 * INV_WIN, a0, a2), EPSV);
        const float jv = fmaxf(fmaf(-a1 * INV_WIN, a1, a3), EPSV);
        lsum += (cross * cross) / (iv * jv);
      }
      a0 += gB0 - rg0[1]; a1 += gB1 - rg1[1]; a2 += gB2 - rg2[1];
      a3 += gB3 - rg3[1]; a4 += gB4 - rg4[1];
      if (ps >= 4) {
        const float cross = fmaf(-a0 * INV_WIN, a1, a4);
        const float iv = fmaxf(fmaf(-a0 * INV_WIN, a0, a2), EPSV);
        const float jv = fmaxf(fmaf(-a1 * INV_WIN, a1, a3), EPSV);
        lsum += (cross * cross) / (iv * jv);
      }
#pragma unroll
      for (int k = 0; k < 7; ++k) {
        rg0[k]=rg0[k+2]; rg1[k]=rg1[k+2]; rg2[k]=rg2[k+2];
        rg3[k]=rg3[k+2]; rg4[k]=rg4[k+2];
      }
      rg0[7]=gA0; rg1[7]=gA1; rg2[7]=gA2; rg3[7]=gA3; rg4[7]=gA4;
      rg0[8]=gB0; rg1[8]=gB1; rg2[8]=gB2; rg3[8]=gB3; rg4[8]=gB4;
    }
    __syncthreads();   // E: S4 scol reads done before S3(ss+1) overwrites;
                       //    srow[(ss)&1] writes visible to S3(ss+1).
  };

  float4 pX0[3], pY0[3], pX1[3], pY1[3];
  prefetch(0 + p2, pX0, pY0);          // pair 0
  prefetch(2 + p2, pX1, pY1);          // pair 1

  for (int ss = 0; ss < NPAIR; ss += 2) {
    body(ss,     true, pX0, pY0);      // consumes buf0, reissues pair ss+2
    body(ss + 1, true, pX1, pY1);      // consumes buf1, reissues pair ss+3
  }
  body(NPAIR, false, pX0, pY0);        // tail: S3/S4 for pair NPAIR-1 only

  // ---- block reduction
#pragma unroll
  for (int off = 32; off > 0; off >>= 1) lsum += __shfl_down(lsum, off);
  if ((tid & 63) == 0) swsum[tid >> 6] = lsum;
  __syncthreads();
  if (tid == 0) {
    const int bid = ((int)blockIdx.z * GY + (int)blockIdx.y) * GX + (int)blockIdx.x;
    bsum[bid] = swsum[0] + swsum[1] + swsum[2] + swsum[3];
  }
}

__global__ __launch_bounds__(256)
void ncc_finalize(const float* __restrict__ bsum, float* __restrict__ out) {
  double s = 0.0;
  for (int i = threadIdx.x; i < NBLK; i += 256) s += (double)bsum[i];
#pragma unroll
  for (int off = 32; off > 0; off >>= 1) s += __shfl_down(s, off);
  __shared__ double sh[4];
  if ((threadIdx.x & 63) == 0) sh[threadIdx.x >> 6] = s;
  __syncthreads();
  if (threadIdx.x == 0)
    out[0] = (float)(-(sh[0] + sh[1] + sh[2] + sh[3]) / NTOT);
}

extern "C" void kernel_launch(void* const* d_in, const int* in_sizes, int n_in,
                              void* d_out, int out_size, void* d_ws, size_t ws_size,
                              hipStream_t stream) {
  const float* x = (const float*)d_in[0];
  const float* y = (const float*)d_in[1];
  float* bsum = (float*)d_ws;          // 1680 floats, fully rewritten every call
  float* out  = (float*)d_out;

  dim3 grid(GX, GY, GZ);
  ncc_fused<<<grid, dim3(256), 0, stream>>>(x, y, bsum);
  ncc_finalize<<<1, dim3(256), 0, stream>>>(bsum, out);
}